// Round 9
// baseline (8258.302 us; speedup 1.0000x reference)
//
#include <hip/hip_runtime.h>
#include <hip/hip_fp16.h>

// Bidirectional 2-layer LSTM: B=32, T=1024, IN=256, H=256.
// ws layout: xg  f16 [2][32][1024][1024]              = 134,217,728 B
//            hbt u64 [2][8][2 parity][4 b][256 j]     =     262,144 B (tagged h)
// total = 134,479,872 B
//
// Tag protocol (per layer, base B): producer at step st stores (B+st+1, h) into
// parity st&1; consumer at step st polls parity (st+1)&1 for tag B+st.
// L0 base=1, L1 base=4096; hbt memset to 0 each launch (replay-safe).
//
// recur8: exchange-path optimization (rounds 3-8 all plateau at 2.3-2.7us/step;
// WRITE_SIZE/FETCH_SIZE show agent-atomics coherence point is L3 -> the h
// round trip dominates). Changes:
//  - 128 pollers, coalesced slots (idx=i*128+p), s_sleep backoff: 4x less L3 storm
//  - lane layout tid = jl*16 + q*4 + kq: kq-partials reduced via shfl_xor,
//    i/f/g/o gathered via shfl -> NO scr, NO second barrier
//  - h-stage LDS double-buffered by parity -> single __syncthreads per step.
//    Safety: stage(st+2) [parity st&1] by thread A happens after barrier(st+1);
//    thread C's compute reads(st) [same parity] complete before C arrives at
//    barrier(st+1); barrier orders C's reads before A's writes.

#define T_LEN 1024
#define BATCH 32
#define HID   256
#define G4    1024

struct __align__(8) Half4 { __half x, y, z, w; };

typedef _Float16 f16x2 __attribute__((ext_vector_type(2)));

__device__ __forceinline__ f16x2 pack_f16x2(float lo, float hi) {
    f16x2 r; r.x = (_Float16)lo; r.y = (_Float16)hi; return r;
}
__device__ __forceinline__ float dot2acc(f16x2 a, f16x2 b, float c) {
#if __has_builtin(__builtin_amdgcn_fdot2)
    return __builtin_amdgcn_fdot2(a, b, c, false);
#else
    return c + (float)a.x * (float)b.x + (float)a.y * (float)b.y;
#endif
}

__device__ __forceinline__ float sigm(float x) { return 1.0f / (1.0f + __expf(-x)); }
__device__ __forceinline__ float tanh_fast(float x) {
    float e = __expf(2.f * x);            // inf-safe
    return 1.f - 2.f / (e + 1.f);
}

// ---- projection: xg[dir][m][n] = sum_k A[m][k]*W[n][k] + bih[n] + bhh[n], stored f16 ----
__global__ __launch_bounds__(256) void proj_kernel(
    const float* __restrict__ A, int K,
    const float* __restrict__ Wf, const float* __restrict__ Wr,
    const float* __restrict__ bih_f, const float* __restrict__ bhh_f,
    const float* __restrict__ bih_r, const float* __restrict__ bhh_r,
    __half* __restrict__ xg)
{
    const int dir = blockIdx.z;
    const float* __restrict__ W   = dir ? Wr    : Wf;
    const float* __restrict__ bih = dir ? bih_r : bih_f;
    const float* __restrict__ bhh = dir ? bhh_r : bhh_f;
    __half* __restrict__ outp = xg + (size_t)dir * ((size_t)BATCH * T_LEN * G4);

    __shared__ float As[32][132];
    __shared__ float Bs[32][132];

    const int tid = threadIdx.x;
    const int tx  = tid & 15;
    const int ty  = tid >> 4;
    const int tx4 = tx * 4;
    const int ty4 = ty * 4;
    const int m0  = blockIdx.y * 128;
    const int n0  = blockIdx.x * 128;

    float acc[8][8];
    #pragma unroll
    for (int i = 0; i < 8; ++i)
        #pragma unroll
        for (int j = 0; j < 8; ++j) acc[i][j] = 0.f;

    for (int k0 = 0; k0 < K; k0 += 32) {
        #pragma unroll
        for (int it = 0; it < 4; ++it) {
            int f   = tid + it * 256;
            int row = f >> 3;
            int c4  = (f & 7) * 4;
            float4 av = *reinterpret_cast<const float4*>(&A[(size_t)(m0 + row) * K + k0 + c4]);
            float4 bv = *reinterpret_cast<const float4*>(&W[(size_t)(n0 + row) * K + k0 + c4]);
            As[c4 + 0][row] = av.x; As[c4 + 1][row] = av.y;
            As[c4 + 2][row] = av.z; As[c4 + 3][row] = av.w;
            Bs[c4 + 0][row] = bv.x; Bs[c4 + 1][row] = bv.y;
            Bs[c4 + 2][row] = bv.z; Bs[c4 + 3][row] = bv.w;
        }
        __syncthreads();
        #pragma unroll
        for (int k = 0; k < 32; ++k) {
            float4 a0 = *reinterpret_cast<const float4*>(&As[k][ty4]);
            float4 a1 = *reinterpret_cast<const float4*>(&As[k][64 + ty4]);
            float4 b0 = *reinterpret_cast<const float4*>(&Bs[k][tx4]);
            float4 b1 = *reinterpret_cast<const float4*>(&Bs[k][64 + tx4]);
            float a[8] = {a0.x,a0.y,a0.z,a0.w,a1.x,a1.y,a1.z,a1.w};
            float b[8] = {b0.x,b0.y,b0.z,b0.w,b1.x,b1.y,b1.z,b1.w};
            #pragma unroll
            for (int i = 0; i < 8; ++i)
                #pragma unroll
                for (int j = 0; j < 8; ++j)
                    acc[i][j] = fmaf(a[i], b[j], acc[i][j]);
        }
        __syncthreads();
    }

    float bb[8];
    #pragma unroll
    for (int j = 0; j < 8; ++j) {
        int n = n0 + ((j < 4) ? (tx4 + j) : (64 + tx4 + (j - 4)));
        bb[j] = bih[n] + bhh[n];
    }
    #pragma unroll
    for (int i = 0; i < 8; ++i) {
        int m = m0 + ((i < 4) ? (ty4 + i) : (64 + ty4 + (i - 4)));
        Half4 v0, v1;
        v0.x = __float2half(acc[i][0] + bb[0]);
        v0.y = __float2half(acc[i][1] + bb[1]);
        v0.z = __float2half(acc[i][2] + bb[2]);
        v0.w = __float2half(acc[i][3] + bb[3]);
        v1.x = __float2half(acc[i][4] + bb[4]);
        v1.y = __float2half(acc[i][5] + bb[5]);
        v1.z = __float2half(acc[i][6] + bb[6]);
        v1.w = __float2half(acc[i][7] + bb[7]);
        *reinterpret_cast<Half4*>(&outp[(size_t)m * G4 + n0 + tx4])      = v0;
        *reinterpret_cast<Half4*>(&outp[(size_t)m * G4 + n0 + 64 + tx4]) = v1;
    }
}

// ---- cooperative recurrence: shfl-reduced gates, 1 barrier/step ----
// bid = a*64 + m*8 + x. gid=(a&1)*8+x: d=gid>>3, g=gid&7; s = m + (a>>1)*8.
// Sync group (d,g) = 16 wgs sharing bid%8 (same-XCD heuristic).
// Lane layout: tid = jl*16 + q*4 + kq. jl=tid>>4 (cell 0..15), q=(tid>>2)&3
// (gate i/f/g/o), kq=tid&3 (k-quarter). Thread holds W[n=q*256+s*16+jl]
// [kq*64..+63] as 32 packed half2 VGPRs; computes partials for 4 batches.
extern "C" __global__ __launch_bounds__(256, 2) void recur8_kernel(
    const __half* __restrict__ xg,
    const float* __restrict__ Whh_f,           // [1024][256]
    const float* __restrict__ Whh_r,
    float* __restrict__ outp,                  // [32][1024][512]
    unsigned long long* __restrict__ hbt,      // [2][8][2][4][256] tagged
    unsigned int tagbase)
{
    __shared__ __half hl[2][4 * 256];   // [parity][b*256 + j]

    const int tid = threadIdx.x;
    const int bid = blockIdx.x;
    const int x = bid & 7, m = (bid >> 3) & 7, a = bid >> 6;
    const int gid = (a & 1) * 8 + x;
    const int d = gid >> 3;
    const int g = gid & 7;
    const int s = m + ((a >> 1) << 3);
    const float* __restrict__ Whh = d ? Whh_r : Whh_f;

    const int jl = tid >> 4;
    const int q  = (tid >> 2) & 3;
    const int kq = tid & 3;
    const int n_my = (q << 8) + s * 16 + jl;      // gate row in W_hh

    // --- one-time: 64 weights (row n_my, k = kq*64..+63) as 32 packed half2 ---
    unsigned wh[32];
    {
        const float* wrow = Whh + (size_t)n_my * HID + kq * 64;
        #pragma unroll
        for (int i = 0; i < 16; ++i) {
            float4 w4 = *reinterpret_cast<const float4*>(&wrow[i * 4]);
            wh[2 * i]     = __builtin_bit_cast(unsigned, pack_f16x2(w4.x, w4.y));
            wh[2 * i + 1] = __builtin_bit_cast(unsigned, pack_f16x2(w4.z, w4.w));
        }
    }
    #pragma unroll
    for (int i = 0; i < 32; ++i) asm volatile("" : "+v"(wh[i]));   // no remat

    unsigned long long* hb = hbt + (size_t)(d * 8 + g) * 2048;   // [parity][4][256]

    // init: h[-1]=0, tag=tagbase, parity 1. Producer lanes (q==0): cell (b=kq, jl).
    if ((tid & 12) == 0) {
        __hip_atomic_store(&hb[1024 + kq * 256 + s * 16 + jl],
                           (unsigned long long)tagbase << 32,
                           __ATOMIC_RELAXED, __HIP_MEMORY_SCOPE_AGENT);
    }

    // xg: thread adds xg(b = g*4 + kq, n_my) into accumulator a_{kq}
    const __half* __restrict__ xgp =
        xg + ((size_t)(d * BATCH + g * 4 + kq)) * T_LEN * G4 + n_my;

    const int lane = tid & 63;
    const int shbase = lane & ~12;       // lane of (jl, q=0, kq) within wave
    float c_state = 0.f;                 // cell (b=kq, s*16+jl); redundant over q

    for (int st = 0; st < T_LEN; ++st) {
        const int t = d ? (T_LEN - 1 - st) : st;

        // prefetch xg (independent of h) before polling
        float xv = __half2float(xgp[(size_t)t * G4]);

        // 128 pollers, coalesced slots idx = i*128+p; stage into hl[st&1]
        if (tid < 128) {
            const unsigned int exp = tagbase + (unsigned)st;
            unsigned long long* hsrc = hb + (size_t)((st + 1) & 1) * 1024;
            __half* dst = hl[st & 1];
            #pragma unroll
            for (int i = 0; i < 8; ++i) {
                const int idx = i * 128 + tid;
                unsigned long long v =
                    __hip_atomic_load(&hsrc[idx], __ATOMIC_RELAXED, __HIP_MEMORY_SCOPE_AGENT);
                while ((unsigned int)(v >> 32) != exp) {
                    __builtin_amdgcn_s_sleep(1);
                    v = __hip_atomic_load(&hsrc[idx], __ATOMIC_RELAXED, __HIP_MEMORY_SCOPE_AGENT);
                }
                dst[idx] = __float2half(__uint_as_float((unsigned int)v));
            }
        }
        __syncthreads();   // hl[st&1] ready; also orders prev-parity reads vs future writes

        // partial dots over this k-quarter, 4 batches, W in 32 VGPRs
        float a0 = (kq == 0) ? xv : 0.f;
        float a1 = (kq == 1) ? xv : 0.f;
        float a2 = (kq == 2) ? xv : 0.f;
        float a3 = (kq == 3) ? xv : 0.f;
        {
            const char* hbase = (const char*)hl[st & 1] + kq * 128;  // + b*512
            #pragma unroll
            for (int i = 0; i < 8; ++i) {
                float4 h0 = *reinterpret_cast<const float4*>(hbase + 0 * 512 + i * 16);
                float4 h1 = *reinterpret_cast<const float4*>(hbase + 1 * 512 + i * 16);
                float4 h2 = *reinterpret_cast<const float4*>(hbase + 2 * 512 + i * 16);
                float4 h3 = *reinterpret_cast<const float4*>(hbase + 3 * 512 + i * 16);
                f16x2 w0 = __builtin_bit_cast(f16x2, wh[i * 4 + 0]);
                f16x2 w1 = __builtin_bit_cast(f16x2, wh[i * 4 + 1]);
                f16x2 w2 = __builtin_bit_cast(f16x2, wh[i * 4 + 2]);
                f16x2 w3 = __builtin_bit_cast(f16x2, wh[i * 4 + 3]);
                a0 = dot2acc(__builtin_bit_cast(f16x2, h0.x), w0, a0);
                a0 = dot2acc(__builtin_bit_cast(f16x2, h0.y), w1, a0);
                a0 = dot2acc(__builtin_bit_cast(f16x2, h0.z), w2, a0);
                a0 = dot2acc(__builtin_bit_cast(f16x2, h0.w), w3, a0);
                a1 = dot2acc(__builtin_bit_cast(f16x2, h1.x), w0, a1);
                a1 = dot2acc(__builtin_bit_cast(f16x2, h1.y), w1, a1);
                a1 = dot2acc(__builtin_bit_cast(f16x2, h1.z), w2, a1);
                a1 = dot2acc(__builtin_bit_cast(f16x2, h1.w), w3, a1);
                a2 = dot2acc(__builtin_bit_cast(f16x2, h2.x), w0, a2);
                a2 = dot2acc(__builtin_bit_cast(f16x2, h2.y), w1, a2);
                a2 = dot2acc(__builtin_bit_cast(f16x2, h2.z), w2, a2);
                a2 = dot2acc(__builtin_bit_cast(f16x2, h2.w), w3, a2);
                a3 = dot2acc(__builtin_bit_cast(f16x2, h3.x), w0, a3);
                a3 = dot2acc(__builtin_bit_cast(f16x2, h3.y), w1, a3);
                a3 = dot2acc(__builtin_bit_cast(f16x2, h3.z), w2, a3);
                a3 = dot2acc(__builtin_bit_cast(f16x2, h3.w), w3, a3);
            }
        }

        // kq-reduce each accumulator across the 4-lane group (in-wave butterfly)
        a0 += __shfl_xor(a0, 1); a0 += __shfl_xor(a0, 2);
        a1 += __shfl_xor(a1, 1); a1 += __shfl_xor(a1, 2);
        a2 += __shfl_xor(a2, 1); a2 += __shfl_xor(a2, 2);
        a3 += __shfl_xor(a3, 1); a3 += __shfl_xor(a3, 2);

        // lane holds full gate_q for 4 batches; select own batch (b = kq)
        float sel = (kq == 0) ? a0 : (kq == 1) ? a1 : (kq == 2) ? a2 : a3;
        // gather i/f/g/o from lanes (jl, q=0..3, same kq)
        float gi = __shfl(sel, shbase);
        float gf = __shfl(sel, shbase + 4);
        float gg = __shfl(sel, shbase + 8);
        float go = __shfl(sel, shbase + 12);

        float ii = sigm(gi);
        float ff = sigm(gf);
        float g2 = tanh_fast(gg);
        float oo = sigm(go);
        c_state = ff * c_state + ii * g2;
        float h = oo * tanh_fast(c_state);

        if ((tid & 12) == 0) {   // producer lanes: cell (b = kq, j = s*16 + jl)
            const int j = s * 16 + jl;
            unsigned long long pv =
                ((unsigned long long)(tagbase + (unsigned)st + 1u) << 32) | __float_as_uint(h);
            __hip_atomic_store(&hb[(size_t)(st & 1) * 1024 + kq * 256 + j], pv,
                               __ATOMIC_RELAXED, __HIP_MEMORY_SCOPE_AGENT);
            const int b = g * 4 + kq;
            outp[((size_t)b * T_LEN + t) * (2 * HID) + d * HID + j] = h;
        }
    }
}

extern "C" void kernel_launch(void* const* d_in, const int* in_sizes, int n_in,
                              void* d_out, int out_size, void* d_ws, size_t ws_size,
                              hipStream_t stream)
{
    const float* x       = (const float*)d_in[0];
    const float* W_ih_f0 = (const float*)d_in[1];
    const float* W_hh_f0 = (const float*)d_in[2];
    const float* b_ih_f0 = (const float*)d_in[3];
    const float* b_hh_f0 = (const float*)d_in[4];
    const float* W_ih_r0 = (const float*)d_in[5];
    const float* W_hh_r0 = (const float*)d_in[6];
    const float* b_ih_r0 = (const float*)d_in[7];
    const float* b_hh_r0 = (const float*)d_in[8];
    const float* W_ih_f1 = (const float*)d_in[9];
    const float* W_hh_f1 = (const float*)d_in[10];
    const float* b_ih_f1 = (const float*)d_in[11];
    const float* b_hh_f1 = (const float*)d_in[12];
    const float* W_ih_r1 = (const float*)d_in[13];
    const float* W_hh_r1 = (const float*)d_in[14];
    const float* b_ih_r1 = (const float*)d_in[15];
    const float* b_hh_r1 = (const float*)d_in[16];

    float* outp = (float*)d_out;

    __half* xg = (__half*)d_ws;
    const size_t xg_bytes = (size_t)2 * BATCH * T_LEN * G4 * sizeof(__half); // 134,217,728
    unsigned long long* hbt = (unsigned long long*)((char*)d_ws + xg_bytes); // 262,144 B

    // clean tag space every launch (no stale-tag pre-match, fully replay-safe)
    hipMemsetAsync(hbt, 0, 262144, stream);

    // ---- layer 0 ----
    proj_kernel<<<dim3(8, 256, 2), 256, 0, stream>>>(x, 256, W_ih_f0, W_ih_r0,
        b_ih_f0, b_hh_f0, b_ih_r0, b_hh_r0, xg);
    {
        const __half* xg_c = xg;
        unsigned int base0 = 1u;
        void* args[] = {(void*)&xg_c, (void*)&W_hh_f0, (void*)&W_hh_r0,
                        (void*)&outp, (void*)&hbt, (void*)&base0};
        hipLaunchCooperativeKernel(reinterpret_cast<const void*>(recur8_kernel),
                                   dim3(256), dim3(256), args, 0, stream);
    }

    // ---- layer 1 ----
    proj_kernel<<<dim3(8, 256, 2), 256, 0, stream>>>(outp, 512, W_ih_f1, W_ih_r1,
        b_ih_f1, b_hh_f1, b_ih_r1, b_hh_r1, xg);
    {
        const __half* xg_c = xg;
        unsigned int base1 = 4096u;
        void* args[] = {(void*)&xg_c, (void*)&W_hh_f1, (void*)&W_hh_r1,
                        (void*)&outp, (void*)&hbt, (void*)&base1};
        hipLaunchCooperativeKernel(reinterpret_cast<const void*>(recur8_kernel),
                                   dim3(256), dim3(256), args, 0, stream);
    }
}

// Round 10
// 4739.794 us; speedup vs baseline: 1.7423x; 1.7423x over previous
//
#include <hip/hip_runtime.h>
#include <hip/hip_fp16.h>

// Bidirectional 2-layer LSTM: B=32, T=1024, IN=256, H=256.
// ws layout: xg  f16 [2][32][1024][1024]          = 134,217,728 B
//            hbt u64 [2][16][2 parity][2 b][256]  =     262,144 B  (tagged h)
// total = 134,479,872 B
//
// Tag protocol (per layer, base B): producer at step st stores (B+st+1, h) into
// parity st&1; consumer at step st polls parity (st+1)&1 for tag B+st.
// L0 base=1, L1 base=4096; hbt memset to 0 each launch (replay-safe).
//
// recur9 = recur4 skeleton (fastest so far: group of 8 wgs, 2 parallel
// polls/thread, scr + 2 barriers) with:
//  - W as 64 packed half2 VGPRs + fdot2 (resident; r8 proved the layout)
//  - own-slot shortcut: the wg's 64 h-values bypass global; producers write
//    them into the parity-double-buffered LDS stage directly
//  - no shfl (r9's 134M bank conflicts), no sequential multi-slot polls (r8/r9)

#define T_LEN 1024
#define BATCH 32
#define HID   256
#define G4    1024
#define NG    16

struct __align__(8) Half4 { __half x, y, z, w; };

typedef _Float16 f16x2 __attribute__((ext_vector_type(2)));

__device__ __forceinline__ f16x2 pack_f16x2(float lo, float hi) {
    f16x2 r; r.x = (_Float16)lo; r.y = (_Float16)hi; return r;
}
__device__ __forceinline__ float dot2acc(f16x2 a, f16x2 b, float c) {
#if __has_builtin(__builtin_amdgcn_fdot2)
    return __builtin_amdgcn_fdot2(a, b, c, false);
#else
    return c + (float)a.x * (float)b.x + (float)a.y * (float)b.y;
#endif
}

__device__ __forceinline__ float sigm(float x) { return 1.0f / (1.0f + __expf(-x)); }
__device__ __forceinline__ float tanh_fast(float x) {
    float e = __expf(2.f * x);            // inf-safe
    return 1.f - 2.f / (e + 1.f);
}

// ---- projection: xg[dir][m][n] = sum_k A[m][k]*W[n][k] + bih[n] + bhh[n], stored f16 ----
__global__ __launch_bounds__(256) void proj_kernel(
    const float* __restrict__ A, int K,
    const float* __restrict__ Wf, const float* __restrict__ Wr,
    const float* __restrict__ bih_f, const float* __restrict__ bhh_f,
    const float* __restrict__ bih_r, const float* __restrict__ bhh_r,
    __half* __restrict__ xg)
{
    const int dir = blockIdx.z;
    const float* __restrict__ W   = dir ? Wr    : Wf;
    const float* __restrict__ bih = dir ? bih_r : bih_f;
    const float* __restrict__ bhh = dir ? bhh_r : bhh_f;
    __half* __restrict__ outp = xg + (size_t)dir * ((size_t)BATCH * T_LEN * G4);

    __shared__ float As[32][132];
    __shared__ float Bs[32][132];

    const int tid = threadIdx.x;
    const int tx  = tid & 15;
    const int ty  = tid >> 4;
    const int tx4 = tx * 4;
    const int ty4 = ty * 4;
    const int m0  = blockIdx.y * 128;
    const int n0  = blockIdx.x * 128;

    float acc[8][8];
    #pragma unroll
    for (int i = 0; i < 8; ++i)
        #pragma unroll
        for (int j = 0; j < 8; ++j) acc[i][j] = 0.f;

    for (int k0 = 0; k0 < K; k0 += 32) {
        #pragma unroll
        for (int it = 0; it < 4; ++it) {
            int f   = tid + it * 256;
            int row = f >> 3;
            int c4  = (f & 7) * 4;
            float4 av = *reinterpret_cast<const float4*>(&A[(size_t)(m0 + row) * K + k0 + c4]);
            float4 bv = *reinterpret_cast<const float4*>(&W[(size_t)(n0 + row) * K + k0 + c4]);
            As[c4 + 0][row] = av.x; As[c4 + 1][row] = av.y;
            As[c4 + 2][row] = av.z; As[c4 + 3][row] = av.w;
            Bs[c4 + 0][row] = bv.x; Bs[c4 + 1][row] = bv.y;
            Bs[c4 + 2][row] = bv.z; Bs[c4 + 3][row] = bv.w;
        }
        __syncthreads();
        #pragma unroll
        for (int k = 0; k < 32; ++k) {
            float4 a0 = *reinterpret_cast<const float4*>(&As[k][ty4]);
            float4 a1 = *reinterpret_cast<const float4*>(&As[k][64 + ty4]);
            float4 b0 = *reinterpret_cast<const float4*>(&Bs[k][tx4]);
            float4 b1 = *reinterpret_cast<const float4*>(&Bs[k][64 + tx4]);
            float a[8] = {a0.x,a0.y,a0.z,a0.w,a1.x,a1.y,a1.z,a1.w};
            float b[8] = {b0.x,b0.y,b0.z,b0.w,b1.x,b1.y,b1.z,b1.w};
            #pragma unroll
            for (int i = 0; i < 8; ++i)
                #pragma unroll
                for (int j = 0; j < 8; ++j)
                    acc[i][j] = fmaf(a[i], b[j], acc[i][j]);
        }
        __syncthreads();
    }

    float bb[8];
    #pragma unroll
    for (int j = 0; j < 8; ++j) {
        int n = n0 + ((j < 4) ? (tx4 + j) : (64 + tx4 + (j - 4)));
        bb[j] = bih[n] + bhh[n];
    }
    #pragma unroll
    for (int i = 0; i < 8; ++i) {
        int m = m0 + ((i < 4) ? (ty4 + i) : (64 + ty4 + (i - 4)));
        Half4 v0, v1;
        v0.x = __float2half(acc[i][0] + bb[0]);
        v0.y = __float2half(acc[i][1] + bb[1]);
        v0.z = __float2half(acc[i][2] + bb[2]);
        v0.w = __float2half(acc[i][3] + bb[3]);
        v1.x = __float2half(acc[i][4] + bb[4]);
        v1.y = __float2half(acc[i][5] + bb[5]);
        v1.z = __float2half(acc[i][6] + bb[6]);
        v1.w = __float2half(acc[i][7] + bb[7]);
        *reinterpret_cast<Half4*>(&outp[(size_t)m * G4 + n0 + tx4])      = v0;
        *reinterpret_cast<Half4*>(&outp[(size_t)m * G4 + n0 + 64 + tx4]) = v1;
    }
}

// ---- cooperative recurrence ----
// wg = (dir d, batch-group g [2 batches], slice s [32 h-idx -> 128 gate cols]).
// bid = a*64 + m*8 + x ; gid = a*8 + x : d=gid>>4, g=gid&15, s=m (group shares
// bid%8 -> same-XCD heuristic).
// thread: col = tid&127 (q=col>>5 gate, jl=col&31, n_my=q*256+s*32+jl),
//         kh = tid>>7 (k-half, wave-uniform -> h reads are broadcasts).
extern "C" __global__ __launch_bounds__(256, 2) void recur9_kernel(
    const __half* __restrict__ xg,
    const float* __restrict__ Whh_f,           // [1024][256]
    const float* __restrict__ Whh_r,
    float* __restrict__ outp,                  // [32][1024][512]
    unsigned long long* __restrict__ hbt,      // [2][16][2][2][256] tagged
    unsigned int tagbase)
{
    __shared__ __half hl[2][512];    // [parity][b*256 + j] staged h (fp16)
    __shared__ float  scr[2 * 256];  // partial gates [kh][b][128 col]

    const int tid = threadIdx.x;
    const int bid = blockIdx.x;
    const int x = bid & 7, m = (bid >> 3) & 7, a = bid >> 6;
    const int gid = a * 8 + x;
    const int d = gid >> 4;
    const int g = gid & 15;
    const int s = m;
    const float* __restrict__ Whh = d ? Whh_r : Whh_f;

    const int col  = tid & 127;
    const int kh   = tid >> 7;                    // k-half 0/1
    const int q    = col >> 5;
    const int jl   = col & 31;
    const int n_my = (q << 8) + s * 32 + jl;      // gate row in W_hh

    // --- one-time: this thread's half W_hh row (128 f32) as 64 packed half2 ---
    unsigned wh[64];
    {
        const float* wrow = Whh + (size_t)n_my * HID + kh * 128;
        #pragma unroll
        for (int i = 0; i < 32; ++i) {
            float4 w4 = *reinterpret_cast<const float4*>(&wrow[i * 4]);
            wh[2 * i]     = __builtin_bit_cast(unsigned, pack_f16x2(w4.x, w4.y));
            wh[2 * i + 1] = __builtin_bit_cast(unsigned, pack_f16x2(w4.z, w4.w));
        }
    }
    #pragma unroll
    for (int i = 0; i < 64; ++i) asm volatile("" : "+v"(wh[i]));   // no remat

    unsigned long long* hb = hbt + (size_t)(d * NG + g) * 1024;  // [parity][2][256]

    // init: h[-1]=0 -> global tag (for the 7 peers) + local LDS parity-0 slots
    const int bi0 = tid >> 5, jl0 = tid & 31;     // epilogue roles (tid<64)
    if (tid < 64) {
        __hip_atomic_store(&hb[512 + bi0 * HID + s * 32 + jl0],
                           (unsigned long long)tagbase << 32,
                           __ATOMIC_RELAXED, __HIP_MEMORY_SCOPE_AGENT);
        hl[0][bi0 * 256 + s * 32 + jl0] = __float2half(0.f);
    }

    // xg: thread adds xg(b = g*2 + kh, n_my) to batch-kh's partial
    const int b_x = g * 2 + kh;
    const __half* __restrict__ xgp =
        xg + ((size_t)(d * BATCH + b_x)) * T_LEN * G4 + n_my;

    const int i0 = tid * 2;              // this thread's 2 exchange slots
    const bool foreign = (((i0 >> 5) & 7) != s);   // slot's owner wg != self
    float c_state = 0.f;                 // tid<64: cell of (bi0, s*32+jl0)

    for (int st = 0; st < T_LEN; ++st) {
        const int t = d ? (T_LEN - 1 - st) : st;

        // prefetch xg (independent of h) before polling
        float xv = __half2float(xgp[(size_t)t * G4]);

        // stage foreign slots of parity (st+1)&1 (tag tagbase+st) into hl[st&1];
        // own 64 slots were written locally by the producers at step st-1 (or init)
        if (foreign) {
            const unsigned int exp = tagbase + (unsigned)st;
            unsigned long long* hsrc = hb + (size_t)((st + 1) & 1) * 512;
            unsigned long long v0 = __hip_atomic_load(&hsrc[i0],     __ATOMIC_RELAXED, __HIP_MEMORY_SCOPE_AGENT);
            unsigned long long v1 = __hip_atomic_load(&hsrc[i0 + 1], __ATOMIC_RELAXED, __HIP_MEMORY_SCOPE_AGENT);
            while ((unsigned int)(v0 >> 32) != exp)
                v0 = __hip_atomic_load(&hsrc[i0],     __ATOMIC_RELAXED, __HIP_MEMORY_SCOPE_AGENT);
            while ((unsigned int)(v1 >> 32) != exp)
                v1 = __hip_atomic_load(&hsrc[i0 + 1], __ATOMIC_RELAXED, __HIP_MEMORY_SCOPE_AGENT);
            hl[st & 1][i0]     = __float2half(__uint_as_float((unsigned int)v0));
            hl[st & 1][i0 + 1] = __float2half(__uint_as_float((unsigned int)v1));
        }
        __syncthreads();   // hl[st&1] complete; also orders same-parity reuse (2-barrier proof)

        // partial dots over this k-half, both batches; W in 64 half2 VGPRs
        float p0 = (kh == 0) ? xv : 0.f, p0b = 0.f;
        float p1 = (kh == 1) ? xv : 0.f, p1b = 0.f;
        {
            const char* h0 = (const char*)(hl[st & 1]) + kh * 256;          // batch 0
            const char* h1 = (const char*)(hl[st & 1]) + 512 + kh * 256;    // batch 1
            #pragma unroll
            for (int i = 0; i < 16; ++i) {
                float4 a4 = *reinterpret_cast<const float4*>(h0 + i * 16);
                float4 b4 = *reinterpret_cast<const float4*>(h1 + i * 16);
                f16x2 w0 = __builtin_bit_cast(f16x2, wh[i * 4 + 0]);
                f16x2 w1 = __builtin_bit_cast(f16x2, wh[i * 4 + 1]);
                f16x2 w2 = __builtin_bit_cast(f16x2, wh[i * 4 + 2]);
                f16x2 w3 = __builtin_bit_cast(f16x2, wh[i * 4 + 3]);
                p0  = dot2acc(__builtin_bit_cast(f16x2, a4.x), w0, p0);
                p0b = dot2acc(__builtin_bit_cast(f16x2, a4.y), w1, p0b);
                p0  = dot2acc(__builtin_bit_cast(f16x2, a4.z), w2, p0);
                p0b = dot2acc(__builtin_bit_cast(f16x2, a4.w), w3, p0b);
                p1  = dot2acc(__builtin_bit_cast(f16x2, b4.x), w0, p1);
                p1b = dot2acc(__builtin_bit_cast(f16x2, b4.y), w1, p1b);
                p1  = dot2acc(__builtin_bit_cast(f16x2, b4.z), w2, p1);
                p1b = dot2acc(__builtin_bit_cast(f16x2, b4.w), w3, p1b);
            }
        }
        scr[kh * 256 +       col] = p0 + p0b;   // batch 0 partial
        scr[kh * 256 + 128 + col] = p1 + p1b;   // batch 1 partial
        __syncthreads();

        if (tid < 64) {
            float gi = scr[bi0 * 128 +       jl0] + scr[256 + bi0 * 128 +       jl0];
            float gf = scr[bi0 * 128 +  32 + jl0] + scr[256 + bi0 * 128 +  32 + jl0];
            float gg = scr[bi0 * 128 +  64 + jl0] + scr[256 + bi0 * 128 +  64 + jl0];
            float go = scr[bi0 * 128 +  96 + jl0] + scr[256 + bi0 * 128 +  96 + jl0];
            float ii = sigm(gi);
            float ff = sigm(gf);
            float g2 = tanh_fast(gg);
            float oo = sigm(go);
            c_state = ff * c_state + ii * g2;
            float h = oo * tanh_fast(c_state);
            int j = s * 32 + jl0;
            // local fast path for own wg (read at step st+1 from hl[(st+1)&1])
            hl[(st + 1) & 1][bi0 * 256 + j] = __float2half(h);
            // global tagged store for the 7 peer wgs
            unsigned long long pv =
                ((unsigned long long)(tagbase + (unsigned)st + 1u) << 32) | __float_as_uint(h);
            __hip_atomic_store(&hb[(size_t)(st & 1) * 512 + bi0 * HID + j], pv,
                               __ATOMIC_RELAXED, __HIP_MEMORY_SCOPE_AGENT);
            int b = g * 2 + bi0;
            outp[((size_t)b * T_LEN + t) * (2 * HID) + d * HID + j] = h;
        }
    }
}

extern "C" void kernel_launch(void* const* d_in, const int* in_sizes, int n_in,
                              void* d_out, int out_size, void* d_ws, size_t ws_size,
                              hipStream_t stream)
{
    const float* x       = (const float*)d_in[0];
    const float* W_ih_f0 = (const float*)d_in[1];
    const float* W_hh_f0 = (const float*)d_in[2];
    const float* b_ih_f0 = (const float*)d_in[3];
    const float* b_hh_f0 = (const float*)d_in[4];
    const float* W_ih_r0 = (const float*)d_in[5];
    const float* W_hh_r0 = (const float*)d_in[6];
    const float* b_ih_r0 = (const float*)d_in[7];
    const float* b_hh_r0 = (const float*)d_in[8];
    const float* W_ih_f1 = (const float*)d_in[9];
    const float* W_hh_f1 = (const float*)d_in[10];
    const float* b_ih_f1 = (const float*)d_in[11];
    const float* b_hh_f1 = (const float*)d_in[12];
    const float* W_ih_r1 = (const float*)d_in[13];
    const float* W_hh_r1 = (const float*)d_in[14];
    const float* b_ih_r1 = (const float*)d_in[15];
    const float* b_hh_r1 = (const float*)d_in[16];

    float* outp = (float*)d_out;

    __half* xg = (__half*)d_ws;
    const size_t xg_bytes = (size_t)2 * BATCH * T_LEN * G4 * sizeof(__half); // 134,217,728
    unsigned long long* hbt = (unsigned long long*)((char*)d_ws + xg_bytes); // 262,144 B

    // clean tag space every launch (no stale-tag pre-match, fully replay-safe)
    hipMemsetAsync(hbt, 0, 262144, stream);

    // ---- layer 0 ----
    proj_kernel<<<dim3(8, 256, 2), 256, 0, stream>>>(x, 256, W_ih_f0, W_ih_r0,
        b_ih_f0, b_hh_f0, b_ih_r0, b_hh_r0, xg);
    {
        const __half* xg_c = xg;
        unsigned int base0 = 1u;
        void* args[] = {(void*)&xg_c, (void*)&W_hh_f0, (void*)&W_hh_r0,
                        (void*)&outp, (void*)&hbt, (void*)&base0};
        hipLaunchCooperativeKernel(reinterpret_cast<const void*>(recur9_kernel),
                                   dim3(256), dim3(256), args, 0, stream);
    }

    // ---- layer 1 ----
    proj_kernel<<<dim3(8, 256, 2), 256, 0, stream>>>(outp, 512, W_ih_f1, W_ih_r1,
        b_ih_f1, b_hh_f1, b_ih_r1, b_hh_r1, xg);
    {
        const __half* xg_c = xg;
        unsigned int base1 = 4096u;
        void* args[] = {(void*)&xg_c, (void*)&W_hh_f1, (void*)&W_hh_r1,
                        (void*)&outp, (void*)&hbt, (void*)&base1};
        hipLaunchCooperativeKernel(reinterpret_cast<const void*>(recur9_kernel),
                                   dim3(256), dim3(256), args, 0, stream);
    }
}

// Round 11
// 3804.971 us; speedup vs baseline: 2.1704x; 1.2457x over previous
//
#include <hip/hip_runtime.h>
#include <hip/hip_fp16.h>

// Bidirectional 2-layer LSTM: B=32, T=1024, IN=256, H=256.
// ws layout: xg  f16 [2][32][1024][1024]        = 134,217,728 B
//            hbt u64 [2][32][2 parity][256 j]   =     262,144 B  (tagged h)
// total = 134,479,872 B
//
// Tag protocol (per layer, base B): producer at step st stores (B+st+1, h) into
// parity st&1; consumer at step st polls parity (st+1)&1 for tag B+st.
// L0 base=1, L1 base=4096; hbt memset to 0 each launch (replay-safe).
// Group-of-4 overwrite safety: I overwrite parity st&1 at step st+2 only after
// my step-(st+2) poll saw ALL peers' tags B+st+2, i.e. every peer finished its
// step-(st+1) compute, which consumed my step-st slots. Safe.
//
// recur10: exchange-topology round. wg = (dir d, batch b, h-quarter jq):
// 256 wgs x 512 threads. All 4 wgs of one (d,b) share bid%8 -> same XCD, so
// the tagged u64 store->poll round trip is XCD-local-L2, not L3 (r9/r10 FETCH
// showed polls missing L2 constantly). Thread = (row r in 256, k-half kh):
// W = 128 fp16 = 64 VGPRs (size class proven resident in r8/r10). Static
// 54 KB LDS pad caps occupancy at 2 blocks/CU at COMPILE TIME -> allocator
// targets <=4 waves/EU -> 128-VGPR budget -> no spill incentive (fixes the
// r5-r7 allocator fight structurally). 192 pollers x 1 slot (max parallel),
// 64 epilogue threads, 2 barriers/step, no shfl.

#define T_LEN 1024
#define BATCH 32
#define HID   256
#define G4    1024

struct __align__(8) Half4 { __half x, y, z, w; };

typedef _Float16 f16x2 __attribute__((ext_vector_type(2)));

__device__ __forceinline__ f16x2 pack_f16x2(float lo, float hi) {
    f16x2 r; r.x = (_Float16)lo; r.y = (_Float16)hi; return r;
}
__device__ __forceinline__ float dot2acc(f16x2 a, f16x2 b, float c) {
#if __has_builtin(__builtin_amdgcn_fdot2)
    return __builtin_amdgcn_fdot2(a, b, c, false);
#else
    return c + (float)a.x * (float)b.x + (float)a.y * (float)b.y;
#endif
}

__device__ __forceinline__ float sigm(float x) { return 1.0f / (1.0f + __expf(-x)); }
__device__ __forceinline__ float tanh_fast(float x) {
    float e = __expf(2.f * x);            // inf-safe
    return 1.f - 2.f / (e + 1.f);
}

// ---- projection: xg[dir][m][n] = sum_k A[m][k]*W[n][k] + bih[n] + bhh[n], stored f16 ----
__global__ __launch_bounds__(256) void proj_kernel(
    const float* __restrict__ A, int K,
    const float* __restrict__ Wf, const float* __restrict__ Wr,
    const float* __restrict__ bih_f, const float* __restrict__ bhh_f,
    const float* __restrict__ bih_r, const float* __restrict__ bhh_r,
    __half* __restrict__ xg)
{
    const int dir = blockIdx.z;
    const float* __restrict__ W   = dir ? Wr    : Wf;
    const float* __restrict__ bih = dir ? bih_r : bih_f;
    const float* __restrict__ bhh = dir ? bhh_r : bhh_f;
    __half* __restrict__ outp = xg + (size_t)dir * ((size_t)BATCH * T_LEN * G4);

    __shared__ float As[32][132];
    __shared__ float Bs[32][132];

    const int tid = threadIdx.x;
    const int tx  = tid & 15;
    const int ty  = tid >> 4;
    const int tx4 = tx * 4;
    const int ty4 = ty * 4;
    const int m0  = blockIdx.y * 128;
    const int n0  = blockIdx.x * 128;

    float acc[8][8];
    #pragma unroll
    for (int i = 0; i < 8; ++i)
        #pragma unroll
        for (int j = 0; j < 8; ++j) acc[i][j] = 0.f;

    for (int k0 = 0; k0 < K; k0 += 32) {
        #pragma unroll
        for (int it = 0; it < 4; ++it) {
            int f   = tid + it * 256;
            int row = f >> 3;
            int c4  = (f & 7) * 4;
            float4 av = *reinterpret_cast<const float4*>(&A[(size_t)(m0 + row) * K + k0 + c4]);
            float4 bv = *reinterpret_cast<const float4*>(&W[(size_t)(n0 + row) * K + k0 + c4]);
            As[c4 + 0][row] = av.x; As[c4 + 1][row] = av.y;
            As[c4 + 2][row] = av.z; As[c4 + 3][row] = av.w;
            Bs[c4 + 0][row] = bv.x; Bs[c4 + 1][row] = bv.y;
            Bs[c4 + 2][row] = bv.z; Bs[c4 + 3][row] = bv.w;
        }
        __syncthreads();
        #pragma unroll
        for (int k = 0; k < 32; ++k) {
            float4 a0 = *reinterpret_cast<const float4*>(&As[k][ty4]);
            float4 a1 = *reinterpret_cast<const float4*>(&As[k][64 + ty4]);
            float4 b0 = *reinterpret_cast<const float4*>(&Bs[k][tx4]);
            float4 b1 = *reinterpret_cast<const float4*>(&Bs[k][64 + tx4]);
            float a[8] = {a0.x,a0.y,a0.z,a0.w,a1.x,a1.y,a1.z,a1.w};
            float b[8] = {b0.x,b0.y,b0.z,b0.w,b1.x,b1.y,b1.z,b1.w};
            #pragma unroll
            for (int i = 0; i < 8; ++i)
                #pragma unroll
                for (int j = 0; j < 8; ++j)
                    acc[i][j] = fmaf(a[i], b[j], acc[i][j]);
        }
        __syncthreads();
    }

    float bb[8];
    #pragma unroll
    for (int j = 0; j < 8; ++j) {
        int n = n0 + ((j < 4) ? (tx4 + j) : (64 + tx4 + (j - 4)));
        bb[j] = bih[n] + bhh[n];
    }
    #pragma unroll
    for (int i = 0; i < 8; ++i) {
        int m = m0 + ((i < 4) ? (ty4 + i) : (64 + ty4 + (i - 4)));
        Half4 v0, v1;
        v0.x = __float2half(acc[i][0] + bb[0]);
        v0.y = __float2half(acc[i][1] + bb[1]);
        v0.z = __float2half(acc[i][2] + bb[2]);
        v0.w = __float2half(acc[i][3] + bb[3]);
        v1.x = __float2half(acc[i][4] + bb[4]);
        v1.y = __float2half(acc[i][5] + bb[5]);
        v1.z = __float2half(acc[i][6] + bb[6]);
        v1.w = __float2half(acc[i][7] + bb[7]);
        *reinterpret_cast<Half4*>(&outp[(size_t)m * G4 + n0 + tx4])      = v0;
        *reinterpret_cast<Half4*>(&outp[(size_t)m * G4 + n0 + 64 + tx4]) = v1;
    }
}

// ---- cooperative recurrence: group-of-4, same-XCD, 512-thread wgs ----
// bid = jq*64 + (d*32 + b): jq = bid>>6, d = (bid>>5)&1, b = bid&31.
// All 4 jq of one (d,b) share bid%8 -> same XCD (perf heuristic only).
// thread: kh = tid>>8 (k-half), r = tid&255 (local row). Gate row
// n = (r>>6)*256 + jq*64 + (r&63). W = n's k-half = 128 fp16 = 64 VGPRs.
// Epilogue: tid<64 -> h_j, j = jq*64 + tid. Pollers: tid in [256,448).
extern "C" __global__ __launch_bounds__(512, 2) void recur10_kernel(
    const __half* __restrict__ xg,
    const float* __restrict__ Whh_f,           // [1024][256]
    const float* __restrict__ Whh_r,
    float* __restrict__ outp,                  // [32][1024][512]
    unsigned long long* __restrict__ hbt,      // [2][32][2][256] tagged
    unsigned int tagbase)
{
    // 54 KB static LDS: used = hl 1 KB + scr 2 KB; the pad caps occupancy at
    // 2 blocks/CU (3*54KB > 160KB) so the allocator's budget is 128 VGPRs.
    __shared__ char smem[55296];
    __half* hl  = (__half*)smem;            // [2 parity][256 j]
    float*  scr = (float*)(smem + 1024);    // [2 kh][256 r]

    const int tid = threadIdx.x;
    const int bid = blockIdx.x;
    const int jq  = bid >> 6;
    const int d   = (bid >> 5) & 1;
    const int b   = bid & 31;
    const float* __restrict__ Whh = d ? Whh_r : Whh_f;

    const int kh = tid >> 8;                  // k-half 0/1 (wave-uniform)
    const int r  = tid & 255;                 // local row
    const int q  = r >> 6;                    // gate 0..3
    const int jl = r & 63;
    const int n_my = (q << 8) + jq * 64 + jl; // global gate row

    // --- one-time: 128 fp16 weights (row n_my, k-half kh) = 64 half2 VGPRs ---
    unsigned wh[64];
    {
        const float* wrow = Whh + (size_t)n_my * HID + kh * 128;
        #pragma unroll
        for (int i = 0; i < 32; ++i) {
            float4 w4 = *reinterpret_cast<const float4*>(&wrow[i * 4]);
            wh[2 * i]     = __builtin_bit_cast(unsigned, pack_f16x2(w4.x, w4.y));
            wh[2 * i + 1] = __builtin_bit_cast(unsigned, pack_f16x2(w4.z, w4.w));
        }
    }
    #pragma unroll
    for (int i = 0; i < 64; ++i) asm volatile("" : "+v"(wh[i]));   // no remat

    unsigned long long* hb = hbt + (size_t)(d * 32 + b) * 512;   // [parity][256]

    // init: h[-1]=0 -> global tag (peers) + local LDS parity-0 own quarter
    if (tid < 64) {
        __hip_atomic_store(&hb[256 + jq * 64 + tid],
                           (unsigned long long)tagbase << 32,
                           __ATOMIC_RELAXED, __HIP_MEMORY_SCOPE_AGENT);
        hl[0 * 256 + jq * 64 + tid] = __float2half(0.f);
    }

    // poller role: tids [256,448) each own ONE foreign slot
    const bool isPoll = (tid >= 256) && (tid < 448);
    int pslot = 0;
    if (isPoll) {
        int u  = tid - 256;            // 0..191
        int fq = u >> 6;               // 0..2
        int qq = fq + (fq >= jq);      // skip own quarter
        pslot  = qq * 64 + (u & 63);
    }

    // xg: kh==0 threads add xg(b, n_my)
    const __half* __restrict__ xgp =
        xg + ((size_t)(d * BATCH + b)) * T_LEN * G4 + n_my;

    float c_state = 0.f;               // tid<64: cell j = jq*64 + tid

    for (int st = 0; st < T_LEN; ++st) {
        const int t = d ? (T_LEN - 1 - st) : st;

        // prefetch xg (independent of h) before polling
        float xv = (kh == 0) ? __half2float(xgp[(size_t)t * G4]) : 0.f;

        __half* hlcur = hl + (st & 1) * 256;

        // stage foreign quarters (parity (st+1)&1, tag tagbase+st); own quarter
        // was written locally by epilogue at st-1 (or init)
        if (isPoll) {
            const unsigned int exp = tagbase + (unsigned)st;
            unsigned long long* src = hb + (size_t)((st + 1) & 1) * 256 + pslot;
            unsigned long long v =
                __hip_atomic_load(src, __ATOMIC_RELAXED, __HIP_MEMORY_SCOPE_AGENT);
            while ((unsigned int)(v >> 32) != exp)
                v = __hip_atomic_load(src, __ATOMIC_RELAXED, __HIP_MEMORY_SCOPE_AGENT);
            hlcur[pslot] = __float2half(__uint_as_float((unsigned int)v));
        }
        __syncthreads();   // hl[st&1] complete

        // 128-k dot: W in 64 half2 VGPRs, h via broadcast ds_read_b128
        float a0 = xv, a1 = 0.f;
        {
            const float4* hp = reinterpret_cast<const float4*>(hlcur + kh * 128);
            #pragma unroll
            for (int i = 0; i < 16; ++i) {
                float4 hv = hp[i];
                a0 = dot2acc(__builtin_bit_cast(f16x2, hv.x), __builtin_bit_cast(f16x2, wh[4 * i + 0]), a0);
                a1 = dot2acc(__builtin_bit_cast(f16x2, hv.y), __builtin_bit_cast(f16x2, wh[4 * i + 1]), a1);
                a0 = dot2acc(__builtin_bit_cast(f16x2, hv.z), __builtin_bit_cast(f16x2, wh[4 * i + 2]), a0);
                a1 = dot2acc(__builtin_bit_cast(f16x2, hv.w), __builtin_bit_cast(f16x2, wh[4 * i + 3]), a1);
            }
        }
        scr[kh * 256 + r] = a0 + a1;
        __syncthreads();

        if (tid < 64) {
            float gi = scr[      tid] + scr[256 +       tid];
            float gf = scr[ 64 + tid] + scr[256 +  64 + tid];
            float gg = scr[128 + tid] + scr[256 + 128 + tid];
            float go = scr[192 + tid] + scr[256 + 192 + tid];
            float ii = sigm(gi);
            float ff = sigm(gf);
            float g2 = tanh_fast(gg);
            float oo = sigm(go);
            c_state = ff * c_state + ii * g2;
            float h = oo * tanh_fast(c_state);
            const int j = jq * 64 + tid;
            // local fast path for own wg (read at st+1 from hl[(st+1)&1])
            hl[((st + 1) & 1) * 256 + j] = __float2half(h);
            // global tagged store for the 3 same-XCD peers
            unsigned long long pv =
                ((unsigned long long)(tagbase + (unsigned)st + 1u) << 32) | __float_as_uint(h);
            __hip_atomic_store(&hb[(size_t)(st & 1) * 256 + j], pv,
                               __ATOMIC_RELAXED, __HIP_MEMORY_SCOPE_AGENT);
            outp[((size_t)b * T_LEN + t) * (2 * HID) + d * HID + j] = h;
        }
        // no 3rd barrier: next step's post-stage barrier orders scr reuse; the
        // epilogue's hl[(st+1)&1] writes are to slots disjoint from pollers'.
    }
}

extern "C" void kernel_launch(void* const* d_in, const int* in_sizes, int n_in,
                              void* d_out, int out_size, void* d_ws, size_t ws_size,
                              hipStream_t stream)
{
    const float* x       = (const float*)d_in[0];
    const float* W_ih_f0 = (const float*)d_in[1];
    const float* W_hh_f0 = (const float*)d_in[2];
    const float* b_ih_f0 = (const float*)d_in[3];
    const float* b_hh_f0 = (const float*)d_in[4];
    const float* W_ih_r0 = (const float*)d_in[5];
    const float* W_hh_r0 = (const float*)d_in[6];
    const float* b_ih_r0 = (const float*)d_in[7];
    const float* b_hh_r0 = (const float*)d_in[8];
    const float* W_ih_f1 = (const float*)d_in[9];
    const float* W_hh_f1 = (const float*)d_in[10];
    const float* b_ih_f1 = (const float*)d_in[11];
    const float* b_hh_f1 = (const float*)d_in[12];
    const float* W_ih_r1 = (const float*)d_in[13];
    const float* W_hh_r1 = (const float*)d_in[14];
    const float* b_ih_r1 = (const float*)d_in[15];
    const float* b_hh_r1 = (const float*)d_in[16];

    float* outp = (float*)d_out;

    __half* xg = (__half*)d_ws;
    const size_t xg_bytes = (size_t)2 * BATCH * T_LEN * G4 * sizeof(__half); // 134,217,728
    unsigned long long* hbt = (unsigned long long*)((char*)d_ws + xg_bytes); // 262,144 B

    // clean tag space every launch (no stale-tag pre-match, fully replay-safe)
    hipMemsetAsync(hbt, 0, 262144, stream);

    // ---- layer 0 ----
    proj_kernel<<<dim3(8, 256, 2), 256, 0, stream>>>(x, 256, W_ih_f0, W_ih_r0,
        b_ih_f0, b_hh_f0, b_ih_r0, b_hh_r0, xg);
    {
        const __half* xg_c = xg;
        unsigned int base0 = 1u;
        void* args[] = {(void*)&xg_c, (void*)&W_hh_f0, (void*)&W_hh_r0,
                        (void*)&outp, (void*)&hbt, (void*)&base0};
        hipLaunchCooperativeKernel(reinterpret_cast<const void*>(recur10_kernel),
                                   dim3(256), dim3(512), args, 0, stream);
    }

    // ---- layer 1 ----
    proj_kernel<<<dim3(8, 256, 2), 256, 0, stream>>>(outp, 512, W_ih_f1, W_ih_r1,
        b_ih_f1, b_hh_f1, b_ih_r1, b_hh_r1, xg);
    {
        const __half* xg_c = xg;
        unsigned int base1 = 4096u;
        void* args[] = {(void*)&xg_c, (void*)&W_hh_f1, (void*)&W_hh_r1,
                        (void*)&outp, (void*)&hbt, (void*)&base1};
        hipLaunchCooperativeKernel(reinterpret_cast<const void*>(recur10_kernel),
                                   dim3(256), dim3(512), args, 0, stream);
    }
}